// Round 2
// baseline (347.238 us; speedup 1.0000x reference)
//
#include <hip/hip_runtime.h>

#define N_VOX  150000
#define KNBR   27
#define CIN    32
#define COUT   64
#define TM     64           // voxels per block tile
#define FS     68           // f_s leading stride (floats): %4==0 for float4, breaks bank aliasing
#define NBUCKET 64
#define NEG_SLOPE 0.01f
#define EPS 1e-5f

// ---------------------------------------------------------------------------
// Kernel 1: gather-conv. One 256-thread block computes a 64x64 output tile.
// Also accumulates per-channel sum / sumsq into bucketed global accumulators.
// ---------------------------------------------------------------------------
__global__ __launch_bounds__(256) void conv_kernel(
    const float* __restrict__ feats,          // [N, CIN]
    const float* __restrict__ W,              // [K, CIN, COUT]
    const int* __restrict__ nbr,              // [N, K]
    const int* __restrict__ mask,             // [N, K] (bool promoted to int32 by harness)
    float* __restrict__ out,                  // [N, COUT] raw conv result
    float* __restrict__ bsums)                // [NBUCKET][2*COUT]
{
    __shared__ float f_s[CIN * FS];        // [c][r] transposed gathered tile
    __shared__ float w_s[CIN * COUT];      // [c][d] W[k] tile

    const int t    = threadIdx.x;
    const int tx   = t & 15;               // col group (4 cols each)
    const int ty   = t >> 4;               // row group (4 rows each)
    const int base = blockIdx.x * TM;

    // gather-stage mapping: 4 threads per voxel row, each loads 8 channels
    const int gr = t >> 2;                 // voxel row 0..63
    const int cq = t & 3;                  // channel quarter
    const int n_g = base + gr;

    float acc[4][4];
#pragma unroll
    for (int i = 0; i < 4; ++i)
#pragma unroll
        for (int j = 0; j < 4; ++j) acc[i][j] = 0.0f;

    for (int k = 0; k < KNBR; ++k) {
        // ---- load stage (global -> regs) ----
        int idx = -1;
        if (n_g < N_VOX) {
            const long off = (long)n_g * KNBR + k;
            if (mask[off] != 0) idx = nbr[off];
        }
        float4 fa = make_float4(0.f, 0.f, 0.f, 0.f);
        float4 fb = fa;
        if (idx >= 0) {
            const float4* fp = reinterpret_cast<const float4*>(feats + (long)idx * CIN + cq * 8);
            fa = fp[0];
            fb = fp[1];
        }
        const float4* wsrc = reinterpret_cast<const float4*>(W + (long)k * CIN * COUT + t * 8);
        const float4 wa = wsrc[0];
        const float4 wb = wsrc[1];

        __syncthreads();   // previous iteration's compute done before overwrite

        // ---- stage into LDS ----
        const int c0 = cq * 8;
        f_s[(c0 + 0) * FS + gr] = fa.x;
        f_s[(c0 + 1) * FS + gr] = fa.y;
        f_s[(c0 + 2) * FS + gr] = fa.z;
        f_s[(c0 + 3) * FS + gr] = fa.w;
        f_s[(c0 + 4) * FS + gr] = fb.x;
        f_s[(c0 + 5) * FS + gr] = fb.y;
        f_s[(c0 + 6) * FS + gr] = fb.z;
        f_s[(c0 + 7) * FS + gr] = fb.w;
        reinterpret_cast<float4*>(w_s + t * 8)[0] = wa;
        reinterpret_cast<float4*>(w_s + t * 8)[1] = wb;

        __syncthreads();

        // ---- compute: 4x4 register outer-product tile ----
#pragma unroll
        for (int c = 0; c < CIN; ++c) {
            const float4 fv = *reinterpret_cast<const float4*>(&f_s[c * FS + ty * 4]);
            const float4 wv = *reinterpret_cast<const float4*>(&w_s[c * COUT + tx * 4]);
            const float fr[4] = {fv.x, fv.y, fv.z, fv.w};
            const float wr[4] = {wv.x, wv.y, wv.z, wv.w};
#pragma unroll
            for (int i = 0; i < 4; ++i)
#pragma unroll
                for (int j = 0; j < 4; ++j)
                    acc[i][j] = fmaf(fr[i], wr[j], acc[i][j]);
        }
    }

    // ---- store raw conv output ----
#pragma unroll
    for (int i = 0; i < 4; ++i) {
        const int n = base + ty * 4 + i;
        if (n < N_VOX) {
            float4 v = make_float4(acc[i][0], acc[i][1], acc[i][2], acc[i][3]);
            *reinterpret_cast<float4*>(out + (long)n * COUT + tx * 4) = v;
        }
    }

    // ---- per-channel partial sums (padded rows contribute exact zeros) ----
    float psum[4], psq[4];
#pragma unroll
    for (int j = 0; j < 4; ++j) {
        psum[j] = acc[0][j] + acc[1][j] + acc[2][j] + acc[3][j];
        psq[j]  = acc[0][j] * acc[0][j] + acc[1][j] * acc[1][j]
                + acc[2][j] * acc[2][j] + acc[3][j] * acc[3][j];
    }

    __syncthreads();   // done reading f_s/w_s; reuse as reduction scratch
    // f_s[0..1023]  = red_sum[ty][d],  w_s[0..1023] = red_sq[ty][d]
    *reinterpret_cast<float4*>(&f_s[ty * 64 + tx * 4]) = make_float4(psum[0], psum[1], psum[2], psum[3]);
    *reinterpret_cast<float4*>(&w_s[ty * 64 + tx * 4]) = make_float4(psq[0], psq[1], psq[2], psq[3]);
    __syncthreads();

    if (t < COUT) {
        float s = 0.f, q = 0.f;
#pragma unroll
        for (int g = 0; g < 16; ++g) {
            s += f_s[g * 64 + t];
            q += w_s[g * 64 + t];
        }
        float* dst = bsums + (blockIdx.x & (NBUCKET - 1)) * (2 * COUT);
        atomicAdd(dst + t, s);
        atomicAdd(dst + COUT + t, q);
    }
}

// ---------------------------------------------------------------------------
// Kernel 2: fold buckets -> per-channel scale/shift
// ---------------------------------------------------------------------------
__global__ __launch_bounds__(64) void stats_kernel(
    const float* __restrict__ bsums,
    const float* __restrict__ gamma,
    const float* __restrict__ beta,
    float* __restrict__ ss)                  // [2*COUT]: scale, shift
{
    const int d = threadIdx.x;
    float s = 0.f, q = 0.f;
    for (int b = 0; b < NBUCKET; ++b) {
        s += bsums[b * (2 * COUT) + d];
        q += bsums[b * (2 * COUT) + COUT + d];
    }
    const float inv_n = 1.0f / (float)N_VOX;
    const float mean  = s * inv_n;
    const float var   = q * inv_n - mean * mean;
    const float scale = gamma[d] * rsqrtf(var + EPS);
    ss[d]        = scale;
    ss[COUT + d] = beta[d] - mean * scale;
}

// ---------------------------------------------------------------------------
// Kernel 3: in-place BN affine + LeakyReLU over d_out
// ---------------------------------------------------------------------------
__global__ __launch_bounds__(256) void bn_apply_kernel(
    float* __restrict__ out,
    const float* __restrict__ ss)
{
    const long i = (long)blockIdx.x * 256 + threadIdx.x;
    const long total4 = (long)N_VOX * COUT / 4;
    if (i >= total4) return;
    float4 v = reinterpret_cast<float4*>(out)[i];
    const int cg = (int)(i & 15);            // which float4 within the 64-channel row
    const float4 sc = reinterpret_cast<const float4*>(ss)[cg];
    const float4 sh = reinterpret_cast<const float4*>(ss + COUT)[cg];
    float x;
    x = fmaf(v.x, sc.x, sh.x); v.x = (x >= 0.f) ? x : NEG_SLOPE * x;
    x = fmaf(v.y, sc.y, sh.y); v.y = (x >= 0.f) ? x : NEG_SLOPE * x;
    x = fmaf(v.z, sc.z, sh.z); v.z = (x >= 0.f) ? x : NEG_SLOPE * x;
    x = fmaf(v.w, sc.w, sh.w); v.w = (x >= 0.f) ? x : NEG_SLOPE * x;
    reinterpret_cast<float4*>(out)[i] = v;
}

// ---------------------------------------------------------------------------
extern "C" void kernel_launch(void* const* d_in, const int* in_sizes, int n_in,
                              void* d_out, int out_size, void* d_ws, size_t ws_size,
                              hipStream_t stream) {
    const float* feats = (const float*)d_in[0];
    const float* W     = (const float*)d_in[1];
    const float* gamma = (const float*)d_in[2];
    const float* beta  = (const float*)d_in[3];
    const int* nbr     = (const int*)d_in[4];
    const int* mask    = (const int*)d_in[5];
    float* out = (float*)d_out;
    float* ws  = (float*)d_ws;

    // ws layout: [NBUCKET][2*COUT] bucketed sums, then [2*COUT] scale/shift
    float* bsums = ws;
    float* ss    = ws + NBUCKET * 2 * COUT;

    hipMemsetAsync(bsums, 0, NBUCKET * 2 * COUT * sizeof(float), stream);

    const int nblocks = (N_VOX + TM - 1) / TM;   // 2344
    conv_kernel<<<nblocks, 256, 0, stream>>>(feats, W, nbr, mask, out, bsums);
    stats_kernel<<<1, 64, 0, stream>>>(bsums, gamma, beta, ss);

    const long total4 = (long)N_VOX * COUT / 4;  // 2,400,000
    bn_apply_kernel<<<(int)((total4 + 255) / 256), 256, 0, stream>>>(out, ss);
}

// Round 3
// 190.449 us; speedup vs baseline: 1.8233x; 1.8233x over previous
//
#include <hip/hip_runtime.h>

#define N_VOX  150000
#define KNBR   27
#define CIN    32
#define COUT   64
#define NBUCKET 64
#define NEG_SLOPE 0.01f
#define EPS 1e-5f

typedef __bf16 bf16x8 __attribute__((ext_vector_type(8)));
typedef float  f32x4  __attribute__((ext_vector_type(4)));

// ===========================================================================
// PATH A: bf16 MFMA pipeline
// ===========================================================================

// feats [N,CIN] f32 -> bf16, 8 elems/thread
__global__ __launch_bounds__(256) void prepack_feats(
    const float* __restrict__ f, __bf16* __restrict__ fb)
{
    const int i = blockIdx.x * 256 + threadIdx.x;     // 600000 total
    if (i >= N_VOX * CIN / 8) return;
    const float4* p = reinterpret_cast<const float4*>(f) + (size_t)i * 2;
    const float4 a = p[0], b = p[1];
    bf16x8 o;
    o[0] = (__bf16)a.x; o[1] = (__bf16)a.y; o[2] = (__bf16)a.z; o[3] = (__bf16)a.w;
    o[4] = (__bf16)b.x; o[5] = (__bf16)b.y; o[6] = (__bf16)b.z; o[7] = (__bf16)b.w;
    reinterpret_cast<bf16x8*>(fb)[i] = o;
}

// W [K,CIN,COUT] f32 -> B-fragment order bf16:
// Wp[((k*4+s)*64 + lane)*8 + j] = W[k][ (lane>>4)*8 + j ][ s*16 + (lane&15) ]
__global__ __launch_bounds__(256) void prepack_w(
    const float* __restrict__ W, __bf16* __restrict__ Wp)
{
    const int u = blockIdx.x * 256 + threadIdx.x;     // 27*4*64 = 6912 total
    if (u >= KNBR * 4 * 64) return;
    const int lane = u & 63, f = u >> 6;
    const int s = f & 3, k = f >> 2;
    const int n = lane & 15, q = lane >> 4;
    const float* src = W + ((size_t)(k * CIN + q * 8) * COUT + s * 16 + n);
    bf16x8 o;
#pragma unroll
    for (int j = 0; j < 8; ++j) o[j] = (__bf16)src[(size_t)j * COUT];
    reinterpret_cast<bf16x8*>(Wp)[u] = o;
}

// One block = 64 voxels x 64 cols. 4 waves, each a 16-row slice.
// Per tap k: A-frag gathered from global bf16 feats, 4 B-frags from prepacked
// Wp, 4x mfma_f32_16x16x32_bf16. No LDS, no barriers.
__global__ __launch_bounds__(256) void conv_mfma(
    const __bf16* __restrict__ fb,            // [N, CIN] bf16
    const __bf16* __restrict__ Wp,            // prepacked B-frags
    const int* __restrict__ nbr,              // [N, K]
    const int* __restrict__ mask,             // [N, K] int32 bool
    float* __restrict__ out,                  // [N, COUT]
    float* __restrict__ bsums)                // [NBUCKET][2*COUT]
{
    const int t    = threadIdx.x;
    const int wave = t >> 6;
    const int lane = t & 63;
    const int n16  = lane & 15;               // A-row within slice / col within subtile
    const int q    = lane >> 4;               // quad
    const int arow = blockIdx.x * 64 + wave * 16 + n16;   // gather row
    const bool rowok = arow < N_VOX;
    const size_t nb = rowok ? (size_t)arow * KNBR : 0;

    const bf16x8* __restrict__ bp = reinterpret_cast<const bf16x8*>(Wp);
    const bf16x8 zv = {};

    f32x4 acc0 = {0.f, 0.f, 0.f, 0.f};
    f32x4 acc1 = {0.f, 0.f, 0.f, 0.f};
    f32x4 acc2 = {0.f, 0.f, 0.f, 0.f};
    f32x4 acc3 = {0.f, 0.f, 0.f, 0.f};

#pragma unroll 3
    for (int k = 0; k < KNBR; ++k) {
        const int  mk = mask[nb + k];
        const int  ix = nbr[nb + k];
        const bool v  = rowok && (mk != 0);
        const int  ie = v ? ix : 0;
        // A fragment: lane holds feats_bf16[row=n16][c = q*8 .. q*8+7]
        bf16x8 a = *reinterpret_cast<const bf16x8*>(fb + (size_t)ie * CIN + q * 8);
        if (!v) a = zv;
        const bf16x8 b0 = bp[(k * 4 + 0) * 64 + lane];
        const bf16x8 b1 = bp[(k * 4 + 1) * 64 + lane];
        const bf16x8 b2 = bp[(k * 4 + 2) * 64 + lane];
        const bf16x8 b3 = bp[(k * 4 + 3) * 64 + lane];
        acc0 = __builtin_amdgcn_mfma_f32_16x16x32_bf16(a, b0, acc0, 0, 0, 0);
        acc1 = __builtin_amdgcn_mfma_f32_16x16x32_bf16(a, b1, acc1, 0, 0, 0);
        acc2 = __builtin_amdgcn_mfma_f32_16x16x32_bf16(a, b2, acc2, 0, 0, 0);
        acc3 = __builtin_amdgcn_mfma_f32_16x16x32_bf16(a, b3, acc3, 0, 0, 0);
    }

    // ---- store: C/D layout col=lane&15, row=quad*4+reg ----
    const int orow_base = blockIdx.x * 64 + wave * 16 + q * 4;
    f32x4 accs[4] = {acc0, acc1, acc2, acc3};
#pragma unroll
    for (int r = 0; r < 4; ++r) {
        const int orow = orow_base + r;
        if (orow < N_VOX) {
            float* dst = out + (size_t)orow * COUT + n16;
#pragma unroll
            for (int s = 0; s < 4; ++s) dst[s * 16] = accs[s][r];
        }
    }

    // ---- per-channel stats: reduce over quads via shuffle, bucketed atomics
    float* dstb = bsums + ((blockIdx.x * 4 + wave) & (NBUCKET - 1)) * (2 * COUT);
#pragma unroll
    for (int s = 0; s < 4; ++s) {
        float ps = accs[s][0] + accs[s][1] + accs[s][2] + accs[s][3];
        float pq = accs[s][0] * accs[s][0] + accs[s][1] * accs[s][1]
                 + accs[s][2] * accs[s][2] + accs[s][3] * accs[s][3];
        ps += __shfl_down(ps, 32); ps += __shfl_down(ps, 16);
        pq += __shfl_down(pq, 32); pq += __shfl_down(pq, 16);
        if (q == 0) {
            atomicAdd(dstb + s * 16 + n16, ps);
            atomicAdd(dstb + COUT + s * 16 + n16, pq);
        }
    }
}

// ===========================================================================
// PATH C fallback: verified fp32 pipeline (round 2)
// ===========================================================================
#define TM 64
#define FS 68
__global__ __launch_bounds__(256) void conv_f32(
    const float* __restrict__ feats, const float* __restrict__ W,
    const int* __restrict__ nbr, const int* __restrict__ mask,
    float* __restrict__ out, float* __restrict__ bsums)
{
    __shared__ float f_s[CIN * FS];
    __shared__ float w_s[CIN * COUT];
    const int t = threadIdx.x;
    const int tx = t & 15, ty = t >> 4;
    const int base = blockIdx.x * TM;
    const int gr = t >> 2, cq = t & 3;
    const int n_g = base + gr;
    float acc[4][4];
#pragma unroll
    for (int i = 0; i < 4; ++i)
#pragma unroll
        for (int j = 0; j < 4; ++j) acc[i][j] = 0.0f;
    for (int k = 0; k < KNBR; ++k) {
        int idx = -1;
        if (n_g < N_VOX) {
            const long off = (long)n_g * KNBR + k;
            if (mask[off] != 0) idx = nbr[off];
        }
        float4 fa = make_float4(0.f, 0.f, 0.f, 0.f);
        float4 fbv = fa;
        if (idx >= 0) {
            const float4* fp = reinterpret_cast<const float4*>(feats + (long)idx * CIN + cq * 8);
            fa = fp[0]; fbv = fp[1];
        }
        const float4* wsrc = reinterpret_cast<const float4*>(W + (long)k * CIN * COUT + t * 8);
        const float4 wa = wsrc[0], wb = wsrc[1];
        __syncthreads();
        const int c0 = cq * 8;
        f_s[(c0 + 0) * FS + gr] = fa.x; f_s[(c0 + 1) * FS + gr] = fa.y;
        f_s[(c0 + 2) * FS + gr] = fa.z; f_s[(c0 + 3) * FS + gr] = fa.w;
        f_s[(c0 + 4) * FS + gr] = fbv.x; f_s[(c0 + 5) * FS + gr] = fbv.y;
        f_s[(c0 + 6) * FS + gr] = fbv.z; f_s[(c0 + 7) * FS + gr] = fbv.w;
        reinterpret_cast<float4*>(w_s + t * 8)[0] = wa;
        reinterpret_cast<float4*>(w_s + t * 8)[1] = wb;
        __syncthreads();
#pragma unroll
        for (int c = 0; c < CIN; ++c) {
            const float4 fv = *reinterpret_cast<const float4*>(&f_s[c * FS + ty * 4]);
            const float4 wv = *reinterpret_cast<const float4*>(&w_s[c * COUT + tx * 4]);
            const float fr[4] = {fv.x, fv.y, fv.z, fv.w};
            const float wr[4] = {wv.x, wv.y, wv.z, wv.w};
#pragma unroll
            for (int i = 0; i < 4; ++i)
#pragma unroll
                for (int j = 0; j < 4; ++j)
                    acc[i][j] = fmaf(fr[i], wr[j], acc[i][j]);
        }
    }
#pragma unroll
    for (int i = 0; i < 4; ++i) {
        const int n = base + ty * 4 + i;
        if (n < N_VOX)
            *reinterpret_cast<float4*>(out + (long)n * COUT + tx * 4) =
                make_float4(acc[i][0], acc[i][1], acc[i][2], acc[i][3]);
    }
    float psum[4], psq[4];
#pragma unroll
    for (int j = 0; j < 4; ++j) {
        psum[j] = acc[0][j] + acc[1][j] + acc[2][j] + acc[3][j];
        psq[j]  = acc[0][j] * acc[0][j] + acc[1][j] * acc[1][j]
                + acc[2][j] * acc[2][j] + acc[3][j] * acc[3][j];
    }
    __syncthreads();
    *reinterpret_cast<float4*>(&f_s[ty * 64 + tx * 4]) = make_float4(psum[0], psum[1], psum[2], psum[3]);
    *reinterpret_cast<float4*>(&w_s[ty * 64 + tx * 4]) = make_float4(psq[0], psq[1], psq[2], psq[3]);
    __syncthreads();
    if (t < COUT) {
        float s = 0.f, qq = 0.f;
#pragma unroll
        for (int g = 0; g < 16; ++g) { s += f_s[g * 64 + t]; qq += w_s[g * 64 + t]; }
        float* dst = bsums + (blockIdx.x & (NBUCKET - 1)) * (2 * COUT);
        atomicAdd(dst + t, s);
        atomicAdd(dst + COUT + t, qq);
    }
}

// ===========================================================================
// Shared: stats fold + BN apply
// ===========================================================================
__global__ __launch_bounds__(64) void stats_kernel(
    const float* __restrict__ bsums, const float* __restrict__ gamma,
    const float* __restrict__ beta, float* __restrict__ ss)
{
    const int d = threadIdx.x;
    float s = 0.f, q = 0.f;
    for (int b = 0; b < NBUCKET; ++b) {
        s += bsums[b * (2 * COUT) + d];
        q += bsums[b * (2 * COUT) + COUT + d];
    }
    const float inv_n = 1.0f / (float)N_VOX;
    const float mean  = s * inv_n;
    const float var   = q * inv_n - mean * mean;
    const float scale = gamma[d] * rsqrtf(var + EPS);
    ss[d]        = scale;
    ss[COUT + d] = beta[d] - mean * scale;
}

__global__ __launch_bounds__(256) void bn_apply_kernel(
    float* __restrict__ out, const float* __restrict__ ss)
{
    const long i = (long)blockIdx.x * 256 + threadIdx.x;
    const long total4 = (long)N_VOX * COUT / 4;
    if (i >= total4) return;
    float4 v = reinterpret_cast<float4*>(out)[i];
    const int cg = (int)(i & 15);
    const float4 sc = reinterpret_cast<const float4*>(ss)[cg];
    const float4 sh = reinterpret_cast<const float4*>(ss + COUT)[cg];
    float x;
    x = fmaf(v.x, sc.x, sh.x); v.x = (x >= 0.f) ? x : NEG_SLOPE * x;
    x = fmaf(v.y, sc.y, sh.y); v.y = (x >= 0.f) ? x : NEG_SLOPE * x;
    x = fmaf(v.z, sc.z, sh.z); v.z = (x >= 0.f) ? x : NEG_SLOPE * x;
    x = fmaf(v.w, sc.w, sh.w); v.w = (x >= 0.f) ? x : NEG_SLOPE * x;
    reinterpret_cast<float4*>(out)[i] = v;
}

// ===========================================================================
extern "C" void kernel_launch(void* const* d_in, const int* in_sizes, int n_in,
                              void* d_out, int out_size, void* d_ws, size_t ws_size,
                              hipStream_t stream) {
    const float* feats = (const float*)d_in[0];
    const float* W     = (const float*)d_in[1];
    const float* gamma = (const float*)d_in[2];
    const float* beta  = (const float*)d_in[3];
    const int* nbr     = (const int*)d_in[4];
    const int* mask    = (const int*)d_in[5];
    float* out = (float*)d_out;
    char* ws   = (char*)d_ws;

    const size_t fb_bytes = (size_t)N_VOX * CIN * sizeof(__bf16);       // 9.6 MB
    const size_t wp_bytes = (size_t)KNBR * 4 * 64 * 8 * sizeof(__bf16); // 110,592 B
    const size_t bs_bytes = (size_t)NBUCKET * 2 * COUT * sizeof(float);
    const size_t ss_bytes = (size_t)2 * COUT * sizeof(float);
    const long total4 = (long)N_VOX * COUT / 4;

    if (ws_size >= fb_bytes + wp_bytes + bs_bytes + ss_bytes) {
        __bf16* fb  = (__bf16*)ws;
        __bf16* Wp  = (__bf16*)(ws + fb_bytes);
        float* bsums = (float*)(ws + fb_bytes + wp_bytes);
        float* ss    = (float*)(ws + fb_bytes + wp_bytes + bs_bytes);
        hipMemsetAsync(bsums, 0, bs_bytes, stream);
        prepack_feats<<<(N_VOX * CIN / 8 + 255) / 256, 256, 0, stream>>>(feats, fb);
        prepack_w<<<(KNBR * 4 * 64 + 255) / 256, 256, 0, stream>>>(W, Wp);
        conv_mfma<<<(N_VOX + 63) / 64, 256, 0, stream>>>(fb, Wp, nbr, mask, out, bsums);
        stats_kernel<<<1, 64, 0, stream>>>(bsums, gamma, beta, ss);
        bn_apply_kernel<<<(int)((total4 + 255) / 256), 256, 0, stream>>>(out, ss);
    } else {
        float* bsums = (float*)ws;
        float* ss    = (float*)(ws + bs_bytes);
        hipMemsetAsync(bsums, 0, bs_bytes, stream);
        conv_f32<<<(N_VOX + TM - 1) / TM, 256, 0, stream>>>(feats, W, nbr, mask, out, bsums);
        stats_kernel<<<1, 64, 0, stream>>>(bsums, gamma, beta, ss);
        bn_apply_kernel<<<(int)((total4 + 255) / 256), 256, 0, stream>>>(out, ss);
    }
}